// Round 6
// baseline (697.697 us; speedup 1.0000x reference)
//
#include <hip/hip_runtime.h>

#define D 128

typedef short short8_t __attribute__((ext_vector_type(8)));
typedef float float4_t __attribute__((ext_vector_type(4)));

// CSR-build bucketing: bucket = dst >> 8 (256 nodes/bucket), NB <= 512
#define BSH 8
#define BSZ 256
#define NBLK_A 256          // blocks for histogram/scatter passes

// ---------------------------------------------------------------- bf16 helpers
__device__ __forceinline__ float bf_lo(unsigned u) { return __uint_as_float(u << 16); }
__device__ __forceinline__ float bf_hi(unsigned u) { return __uint_as_float(u & 0xffff0000u); }
__device__ __forceinline__ unsigned to_bf1(float x) {           // RNE round to bf16
    unsigned b = __float_as_uint(x);
    return (b + 0x7fffu + ((b >> 16) & 1u)) >> 16;
}
__device__ __forceinline__ unsigned pack2(float a, float b) {
    return to_bf1(a) | (to_bf1(b) << 16);
}

// ---------------------------------------------------------------- utilities

__global__ void f32_to_bf16(const float4* __restrict__ in, uint2* __restrict__ out, long n4) {
    long i = (long)blockIdx.x * blockDim.x + threadIdx.x;
    long stride = (long)gridDim.x * blockDim.x;
    for (; i < n4; i += stride) {
        float4 v = in[i];
        out[i] = make_uint2(pack2(v.x, v.y), pack2(v.z, v.w));
    }
}

// Pack W (L x 128 x 128 fp32) into MFMA B-fragment stream.
__global__ void wpack(const float* __restrict__ W, uint4* __restrict__ Wpk, int L_) {
    int id = blockIdx.x * blockDim.x + threadIdx.x;
    if (id >= L_ * 2048) return;
    int lane = id & 63, cc = (id >> 6) & 3, t = (id >> 8) & 7, l = id >> 11;
    int n = t * 16 + (lane & 15);
    int k0 = cc * 32 + (lane >> 4) * 8;
    const float* Wb = W + (long)l * D * D;
    unsigned u0 = pack2(Wb[(long)(k0 + 0) * D + n], Wb[(long)(k0 + 1) * D + n]);
    unsigned u1 = pack2(Wb[(long)(k0 + 2) * D + n], Wb[(long)(k0 + 3) * D + n]);
    unsigned u2 = pack2(Wb[(long)(k0 + 4) * D + n], Wb[(long)(k0 + 5) * D + n]);
    unsigned u3 = pack2(Wb[(long)(k0 + 6) * D + n], Wb[(long)(k0 + 7) * D + n]);
    Wpk[id] = make_uint4(u0, u1, u2, u3);
}

// ---------------------------------------------------------------- CSR build (bucketed)

__global__ __launch_bounds__(256)
void csr_hist(const int* __restrict__ dst, int* __restrict__ Hist, int E_, int chunk) {
    __shared__ int h[512];
    int b = blockIdx.x, t = threadIdx.x;
    h[t] = 0; h[t + 256] = 0;
    __syncthreads();
    int base = b * chunk;
    int end = base + chunk; if (end > E_) end = E_;
    for (int i = base + t; i < end; i += 256)
        atomicAdd(&h[dst[i] >> BSH], 1);
    __syncthreads();
    Hist[b * 512 + t] = h[t];
    Hist[b * 512 + t + 256] = h[t + 256];
}

__global__ __launch_bounds__(256)
void csr_scan_blocks(int* __restrict__ Hist, int* __restrict__ Tot) {
    __shared__ int sc[256];
    int bkt = blockIdx.x, t = threadIdx.x;
    int v = Hist[t * 512 + bkt];
    sc[t] = v; __syncthreads();
    for (int off = 1; off < 256; off <<= 1) {
        int u = (t >= off) ? sc[t - off] : 0;
        __syncthreads();
        sc[t] += u;
        __syncthreads();
    }
    Hist[t * 512 + bkt] = sc[t] - v;          // exclusive
    if (t == 255) Tot[bkt] = sc[255];
}

__global__ __launch_bounds__(512)
void csr_scan_base(const int* __restrict__ Tot, int* __restrict__ Base, int NB) {
    __shared__ int sc[512];
    int t = threadIdx.x;
    int v = (t < NB) ? Tot[t] : 0;
    sc[t] = v; __syncthreads();
    for (int off = 1; off < 512; off <<= 1) {
        int u = (t >= off) ? sc[t - off] : 0;
        __syncthreads();
        sc[t] += u;
        __syncthreads();
    }
    Base[t] = sc[t] - v;
    if (t == NB - 1) Base[NB] = sc[t];
}

__global__ __launch_bounds__(256)
void csr_scatter(const int* __restrict__ src, const int* __restrict__ dst,
                 const int* __restrict__ Hist, const int* __restrict__ Base,
                 unsigned* __restrict__ EdgeBuf, int E_, int chunk) {
    __shared__ int cur[512];
    int b = blockIdx.x, t = threadIdx.x;
    cur[t]       = Base[t]       + Hist[b * 512 + t];
    cur[t + 256] = Base[t + 256] + Hist[b * 512 + t + 256];
    __syncthreads();
    int base = b * chunk;
    int end = base + chunk; if (end > E_) end = E_;
    for (int i = base + t; i < end; i += 256) {
        int s = src[i], dd = dst[i];
        int p = atomicAdd(&cur[dd >> BSH], 1);
        EdgeBuf[p] = (unsigned)s | ((unsigned)(dd & (BSZ - 1)) << 24);
    }
}

__global__ __launch_bounds__(256)
void csr_fill(const unsigned* __restrict__ EdgeBuf, const int* __restrict__ Base,
              int* __restrict__ rowptr, int* __restrict__ csr, int N_, int E_) {
    __shared__ int deg[256];
    __shared__ int cur[256];
    int b = blockIdx.x, t = threadIdx.x;
    int e0 = Base[b], e1 = Base[b + 1];
    deg[t] = 0;
    __syncthreads();
    for (int i = e0 + t; i < e1; i += 256)
        atomicAdd(&deg[EdgeBuf[i] >> 24], 1);
    __syncthreads();
    int v = deg[t];
    cur[t] = v; __syncthreads();
    for (int off = 1; off < 256; off <<= 1) {
        int u = (t >= off) ? cur[t - off] : 0;
        __syncthreads();
        cur[t] += u;
        __syncthreads();
    }
    int excl = cur[t] - v;
    int node = b * BSZ + t;
    if (node < N_) rowptr[node] = e0 + excl;
    cur[t] = e0 + excl;
    __syncthreads();
    for (int i = e0 + t; i < e1; i += 256) {
        unsigned ev = EdgeBuf[i];
        int p = atomicAdd(&cur[ev >> 24], 1);
        csr[p] = (int)(ev & 0x00FFFFFFu);
    }
    if (b == 0 && t == 0) rowptr[N_] = E_;
}

// ---------------------------------------------------------------- graph segment starts (both arrays)
__global__ void find_starts2(const int* __restrict__ g1, int n1,
                             const int* __restrict__ g2, int n2,
                             int G_, int* __restrict__ s1, int* __restrict__ s2) {
    int id = blockIdx.x * blockDim.x + threadIdx.x;
    if (id >= 2 * (G_ + 1)) return;
    const int* arr; int n; int* out; int g;
    if (id <= G_) { arr = g1; n = n1; out = s1; g = id; }
    else { arr = g2; n = n2; out = s2; g = id - (G_ + 1); }
    if (g == G_) { out[g] = n; return; }
    int lo = 0, hi = n;
    while (lo < hi) { int mid = (lo + hi) >> 1; if (arr[mid] < g) lo = mid + 1; else hi = mid; }
    out[g] = lo;
}

// ---------------------------------------------------------------- ctx prep
// ctxT[l][g] = (segsum(init_feat)[g] + h_lead) @ Wc[l] + b[l]   for all layers
__global__ __launch_bounds__(128)
void ctx_prep(const float* __restrict__ initf, const int* __restrict__ istart,
              const float* __restrict__ leadf, int NL,
              const float* __restrict__ Wc, const float* __restrict__ bb, int L_,
              float* __restrict__ ctxT) {
    __shared__ float cs[D];
    int g = blockIdx.x, t = threadIdx.x;
    float hl = 0.f;
    for (int r = 0; r < NL; ++r) hl += leadf[(long)r * D + t];
    int r0 = istart[g], r1 = istart[g + 1];
    float a0 = 0.f, a1 = 0.f, a2 = 0.f, a3 = 0.f;
    int r = r0;
    for (; r + 4 <= r1; r += 4) {
        a0 += initf[(long)r * D + t];
        a1 += initf[(long)(r + 1) * D + t];
        a2 += initf[(long)(r + 2) * D + t];
        a3 += initf[(long)(r + 3) * D + t];
    }
    for (; r < r1; ++r) a0 += initf[(long)r * D + t];
    cs[t] = hl + (a0 + a1) + (a2 + a3);
    __syncthreads();
    for (int l = 0; l < L_; ++l) {
        const float* Wcl = Wc + (long)l * D * D;
        float p0 = 0.f, p1 = 0.f, p2 = 0.f, p3 = 0.f;
        for (int k = 0; k < D; k += 4) {
            p0 += cs[k]     * Wcl[(long)k * D + t];
            p1 += cs[k + 1] * Wcl[(long)(k + 1) * D + t];
            p2 += cs[k + 2] * Wcl[(long)(k + 2) * D + t];
            p3 += cs[k + 3] * Wcl[(long)(k + 3) * D + t];
        }
        ctxT[((long)l * gridDim.x + g) * D + t] = bb[l * D + t] + (p0 + p1) + (p2 + p3);
    }
}

// ---------------------------------------------------------------- per-layer graph term
// T[g] = segsum_bf(h)[g] @ Wl + ctxT_l[g]
__global__ __launch_bounds__(128)
void segsum_T(const unsigned* __restrict__ hb, const int* __restrict__ start,
              const float* __restrict__ Wl, const float* __restrict__ ctxT_l,
              float* __restrict__ T) {
    __shared__ float part[2][64][2];
    __shared__ float xs[D];
    int g = blockIdx.x, t = threadIdx.x;
    int c = t & 63, half = t >> 6;
    int r0 = start[g], r1 = start[g + 1];
    float l0=0,h0=0,l1=0,h1=0,l2=0,h2=0,l3=0,h3=0;
    int r = r0 + half;
    for (; r + 6 < r1; r += 8) {
        unsigned a = hb[(long)r * 64 + c];
        unsigned bq = hb[(long)(r + 2) * 64 + c];
        unsigned cq = hb[(long)(r + 4) * 64 + c];
        unsigned dq = hb[(long)(r + 6) * 64 + c];
        l0 += bf_lo(a);  h0 += bf_hi(a);
        l1 += bf_lo(bq); h1 += bf_hi(bq);
        l2 += bf_lo(cq); h2 += bf_hi(cq);
        l3 += bf_lo(dq); h3 += bf_hi(dq);
    }
    for (; r < r1; r += 2) { unsigned a = hb[(long)r * 64 + c]; l0 += bf_lo(a); h0 += bf_hi(a); }
    part[half][c][0] = (l0 + l1) + (l2 + l3);
    part[half][c][1] = (h0 + h1) + (h2 + h3);
    __syncthreads();
    xs[t] = part[0][t >> 1][t & 1] + part[1][t >> 1][t & 1];
    __syncthreads();
    float p0=0,p1=0,p2=0,p3=0;
    for (int k = 0; k < D; k += 4) {
        p0 += xs[k]     * Wl[(long)k * D + t];
        p1 += xs[k + 1] * Wl[(long)(k + 1) * D + t];
        p2 += xs[k + 2] * Wl[(long)(k + 2) * D + t];
        p3 += xs[k + 3] * Wl[(long)(k + 3) * D + t];
    }
    T[(long)g * D + t] = ctxT_l[(long)g * D + t] + (p0 + p1) + (p2 + p3);
}

// ---------------------------------------------------------------- readout
__global__ __launch_bounds__(128)
void readout(const unsigned* __restrict__ hb, const int* __restrict__ start,
             const float* __restrict__ f1w, const float* __restrict__ f1b,
             const float* __restrict__ f2w, const float* __restrict__ f2b,
             float* __restrict__ out) {
    __shared__ float part[2][64][2];
    __shared__ float xs[D];
    __shared__ float zs[D];
    int g = blockIdx.x, t = threadIdx.x;
    int c = t & 63, half = t >> 6;
    int r0 = start[g], r1 = start[g + 1];
    float l0=0,h0=0,l1=0,h1=0;
    int r = r0 + half;
    for (; r + 2 < r1; r += 4) {
        unsigned a = hb[(long)r * 64 + c];
        unsigned bq = hb[(long)(r + 2) * 64 + c];
        l0 += bf_lo(a);  h0 += bf_hi(a);
        l1 += bf_lo(bq); h1 += bf_hi(bq);
    }
    if (r < r1) { unsigned a = hb[(long)r * 64 + c]; l0 += bf_lo(a); h0 += bf_hi(a); }
    part[half][c][0] = l0 + l1;
    part[half][c][1] = h0 + h1;
    __syncthreads();
    xs[t] = part[0][t >> 1][t & 1] + part[1][t >> 1][t & 1];
    __syncthreads();
    float p0=0,p1=0,p2=0,p3=0;
    for (int k = 0; k < D; k += 4) {
        p0 += xs[k]     * f1w[(long)k * D + t];
        p1 += xs[k + 1] * f1w[(long)(k + 1) * D + t];
        p2 += xs[k + 2] * f1w[(long)(k + 2) * D + t];
        p3 += xs[k + 3] * f1w[(long)(k + 3) * D + t];
    }
    zs[t] = fmaxf(f1b[t] + (p0 + p1) + (p2 + p3), 0.f);
    __syncthreads();
    float q0=0,q1=0,q2=0,q3=0;
    for (int k = 0; k < D; k += 4) {
        q0 += zs[k]     * f2w[(long)k * D + t];
        q1 += zs[k + 1] * f2w[(long)(k + 1) * D + t];
        q2 += zs[k + 2] * f2w[(long)(k + 2) * D + t];
        q3 += zs[k + 3] * f2w[(long)(k + 3) * D + t];
    }
    out[(long)g * D + t] = f2b[t] + (q0 + q1) + (q2 + q3);
}

// ---------------------------------------------------------------- fused GIN layer (bf16 h, MFMA)
// 128 threads = 2 waves; each wave owns 16 rows. Paired gather: lanes 0-31
// process edge j, lanes 32-63 edge j+1, uint2 (8B) per lane -> one load
// instruction gathers two full 256B rows.
#define TROWS 32
__global__ __launch_bounds__(128, 6)
void layer_kernel(const unsigned* __restrict__ hb, const uint4* __restrict__ Wpk_l,
                  const float* __restrict__ T, const int* __restrict__ gids,
                  const int* __restrict__ rowptr, const int* __restrict__ csr,
                  const float* __restrict__ eps_l, unsigned* __restrict__ houtb, int n) {
    __shared__ __align__(16) unsigned Minb[TROWS][68];
    int tid = threadIdx.x;
    int w = tid >> 6, lane = tid & 63;
    int pl = lane & 31;
    int w16 = w * 16;
    int rowBase = blockIdx.x * TROWS;
    int rb = rowBase + w16;
    float epsv = 1.0f + *eps_l;

    int rp = rb + lane; if (rp > n) rp = n;
    int evv = rowptr[rp];

    int e0 = __shfl(evv, 0);
    int e1 = __shfl(evv, 1);
    int idxv = (e0 + lane < e1) ? csr[e0 + lane] : 0;

    for (int i = 0; i < 16; ++i) {
        int r = rb + i;
        int deg = e1 - e0;
        int e0n = __shfl(evv, i + 1);
        int e1n = __shfl(evv, i + 2);
        int idxn = (e0n + lane < e1n) ? csr[e0n + lane] : 0;
        unsigned su = (r < n) ? hb[(long)r * 64 + lane] : 0u;
        float ax0=0, ay0=0, ax1=0, ay1=0;   // chain A: uints 2pl / 2pl+1, lo/hi
        float bx0=0, by0=0, bx1=0, by1=0;   // chain B
        if (r < n) {
            int iv = idxv;
            int base = 0;
            while (true) {
                int m = deg - base; if (m > 64) m = 64;
                int j = 0;
                for (; j + 4 <= m; j += 4) {
                    int sa0 = __shfl(iv, j+0), sa1 = __shfl(iv, j+1);
                    int sb0 = __shfl(iv, j+2), sb1 = __shfl(iv, j+3);
                    int sA = (lane & 32) ? sa1 : sa0;
                    int sB = (lane & 32) ? sb1 : sb0;
                    uint2 uA = *(const uint2*)(hb + (long)sA * 64 + pl * 2);
                    uint2 uB = *(const uint2*)(hb + (long)sB * 64 + pl * 2);
                    ax0 += bf_lo(uA.x); ay0 += bf_hi(uA.x);
                    ax1 += bf_lo(uA.y); ay1 += bf_hi(uA.y);
                    bx0 += bf_lo(uB.x); by0 += bf_hi(uB.x);
                    bx1 += bf_lo(uB.y); by1 += bf_hi(uB.y);
                }
                for (; j + 2 <= m; j += 2) {
                    int sa0 = __shfl(iv, j), sa1 = __shfl(iv, j+1);
                    int sA = (lane & 32) ? sa1 : sa0;
                    uint2 uA = *(const uint2*)(hb + (long)sA * 64 + pl * 2);
                    ax0 += bf_lo(uA.x); ay0 += bf_hi(uA.x);
                    ax1 += bf_lo(uA.y); ay1 += bf_hi(uA.y);
                }
                if (j < m) {            // odd leftover: low half only
                    int s = __shfl(iv, j);
                    if (!(lane & 32)) {
                        uint2 u = *(const uint2*)(hb + (long)s * 64 + pl * 2);
                        ax0 += bf_lo(u.x); ay0 += bf_hi(u.x);
                        ax1 += bf_lo(u.y); ay1 += bf_hi(u.y);
                    }
                }
                base += 64;
                if (base >= deg) break;
                int mm = deg - base;
                iv = (lane < mm) ? csr[e0 + base + lane] : 0;
            }
        }
        float s0 = ax0 + bx0, s1 = ay0 + by0, s2 = ax1 + bx1, s3 = ay1 + by1;
        s0 += __shfl_xor(s0, 32); s1 += __shfl_xor(s1, 32);
        s2 += __shfl_xor(s2, 32); s3 += __shfl_xor(s3, 32);
        unsigned ue = __shfl(su, 2 * pl);
        unsigned uo = __shfl(su, 2 * pl + 1);
        s0 += epsv * bf_lo(ue); s1 += epsv * bf_hi(ue);
        s2 += epsv * bf_lo(uo); s3 += epsv * bf_hi(uo);
        if (!(lane & 32))
            *(uint2*)&Minb[w16 + i][2 * pl] = make_uint2(pack2(s0, s1), pack2(s2, s3));
        e0 = e0n; e1 = e1n; idxv = idxn;
    }
    // No barrier: each wave's rows are private.

    int m_ = lane & 15, quad = lane >> 4;
    float4_t acc[8];
    #pragma unroll
    for (int tt = 0; tt < 8; ++tt) { acc[tt][0]=0.f; acc[tt][1]=0.f; acc[tt][2]=0.f; acc[tt][3]=0.f; }

    #pragma unroll
    for (int cc = 0; cc < 4; ++cc) {
        short8_t af = *(const short8_t*)&Minb[w16 + m_][cc * 16 + quad * 4];
        #pragma unroll
        for (int tt = 0; tt < 8; ++tt) {
            short8_t bf = *(const short8_t*)&Wpk_l[(tt * 4 + cc) * 64 + lane];
            acc[tt] = __builtin_amdgcn_mfma_f32_16x16x32_bf16(af, bf, acc[tt], 0, 0, 0);
        }
    }

    // Epilogue: T rows usually uniform within a wave's 16 rows.
    int g0 = 0; bool uni = false;
    if (rb < n) {
        int lastr = rb + 15 < n ? rb + 15 : n - 1;
        g0 = gids[rb];
        uni = (g0 == gids[lastr]);
    }
    int gq[4];
    if (!uni) {
        #pragma unroll
        for (int reg = 0; reg < 4; ++reg) {
            int r = rb + quad * 4 + reg;
            gq[reg] = (r < n) ? gids[r] : 0;
        }
    }
    #pragma unroll
    for (int tt = 0; tt < 8; ++tt) {
        int col = tt * 16 + m_;
        float t0, t1, t2, t3;
        if (uni) {
            float tv = T[(long)g0 * D + col];
            t0 = t1 = t2 = t3 = tv;
        } else {
            t0 = T[(long)gq[0] * D + col];
            t1 = T[(long)gq[1] * D + col];
            t2 = T[(long)gq[2] * D + col];
            t3 = T[(long)gq[3] * D + col];
        }
        float v0 = fmaxf(acc[tt][0] + t0, 0.f);
        float v1 = fmaxf(acc[tt][1] + t1, 0.f);
        float v2 = fmaxf(acc[tt][2] + t2, 0.f);
        float v3 = fmaxf(acc[tt][3] + t3, 0.f);
        float w0 = __shfl_xor(v0, 1);
        float w1 = __shfl_xor(v1, 1);
        float w2 = __shfl_xor(v2, 1);
        float w3 = __shfl_xor(v3, 1);
        if (!(lane & 1)) {
            int cu = tt * 8 + (m_ >> 1);
            Minb[w16 + quad * 4 + 0][cu] = pack2(v0, w0);
            Minb[w16 + quad * 4 + 1][cu] = pack2(v1, w1);
            Minb[w16 + quad * 4 + 2][cu] = pack2(v2, w2);
            Minb[w16 + quad * 4 + 3][cu] = pack2(v3, w3);
        }
    }
    #pragma unroll
    for (int rr = 0; rr < 4; ++rr) {
        int lrow = rr * 4 + (lane >> 4);
        int r = rowBase + w16 + lrow;
        if (r < n) {
            uint4 v = *(const uint4*)&Minb[w16 + lrow][(lane & 15) * 4];
            *(uint4*)&houtb[(long)r * 64 + (lane & 15) * 4] = v;
        }
    }
}

// ---------------------------------------------------------------- launch

static inline size_t align512(size_t x) { return (x + 511) & ~(size_t)511; }

extern "C" void kernel_launch(void* const* d_in, const int* in_sizes, int n_in,
                              void* d_out, int out_size, void* d_ws, size_t ws_size,
                              hipStream_t stream) {
    const float* x        = (const float*)d_in[0];
    const int*   src      = (const int*)d_in[1];
    const int*   dst      = (const int*)d_in[2];
    const int*   gids     = (const int*)d_in[3];
    const float* initf    = (const float*)d_in[4];
    const int*   init_gid = (const int*)d_in[5];
    const float* leadf    = (const float*)d_in[6];
    const float* W        = (const float*)d_in[7];
    const float* Wc       = (const float*)d_in[8];
    const float* b        = (const float*)d_in[9];
    const float* eps      = (const float*)d_in[10];
    const float* fc1_w    = (const float*)d_in[11];
    const float* fc1_b    = (const float*)d_in[12];
    const float* fc2_w    = (const float*)d_in[13];
    const float* fc2_b    = (const float*)d_in[14];
    float* out = (float*)d_out;

    const int N  = in_sizes[0] / D;
    const int E  = in_sizes[1];
    const int NI = in_sizes[4] / D;
    const int NL = in_sizes[6] / D;
    const int L  = in_sizes[10];

    // workspace carve-up
    char* p = (char*)d_ws;
    unsigned* xb  = (unsigned*)p; p += align512((size_t)N * 64 * 4);
    unsigned* hAb = (unsigned*)p; p += align512((size_t)N * 64 * 4);
    unsigned* hBb = (unsigned*)p; p += align512((size_t)N * 64 * 4);
    const int G = 1024;
    float* T     = (float*)p; p += align512((size_t)G * D * 4);
    float* ctxT  = (float*)p; p += align512((size_t)L * G * D * 4);
    int* rowptr  = (int*)p;   p += align512((size_t)(N + 1) * 4);
    int* csr     = (int*)p;   p += align512((size_t)E * 4);
    unsigned* EdgeBuf = (unsigned*)p; p += align512((size_t)E * 4);
    int* Hist    = (int*)p;   p += align512((size_t)NBLK_A * 512 * 4);
    int* Tot     = (int*)p;   p += align512((size_t)520 * 4);
    int* Base    = (int*)p;   p += align512((size_t)520 * 4);
    int* nstart  = (int*)p;   p += align512((size_t)(G + 1) * 4);
    int* istart  = (int*)p;   p += align512((size_t)(G + 1) * 4);
    uint4* Wpk   = (uint4*)p; p += align512((size_t)L * 2048 * 16);
    (void)ws_size; (void)n_in;

    const int NB = (N + BSZ - 1) / BSZ;
    const int chunk = (E + NBLK_A - 1) / NBLK_A;

    // ---- CSR build (bucketed)
    csr_hist<<<NBLK_A, 256, 0, stream>>>(dst, Hist, E, chunk);
    csr_scan_blocks<<<NB, 256, 0, stream>>>(Hist, Tot);
    csr_scan_base<<<1, 512, 0, stream>>>(Tot, Base, NB);
    csr_scatter<<<NBLK_A, 256, 0, stream>>>(src, dst, Hist, Base, EdgeBuf, E, chunk);
    csr_fill<<<NB, 256, 0, stream>>>(EdgeBuf, Base, rowptr, csr, N, E);

    // ---- bf16 copy of x; packed W fragments; segment starts
    f32_to_bf16<<<2048, 256, 0, stream>>>((const float4*)x, (uint2*)xb, (long)N * D / 4);
    wpack<<<(L * 2048 + 255) / 256, 256, 0, stream>>>(W, Wpk, L);
    find_starts2<<<(2 * (G + 1) + 255) / 256, 256, 0, stream>>>(gids, N, init_gid, NI,
                                                                G, nstart, istart);

    // ---- layer-invariant context terms (all layers)
    ctx_prep<<<G, D, 0, stream>>>(initf, istart, leadf, NL, Wc, b, L, ctxT);

    const unsigned* hcur = xb;
    unsigned* bufs[2] = { hAb, hBb };
    int layerBlocks = (N + TROWS - 1) / TROWS;
    for (int l = 0; l < L; ++l) {
        segsum_T<<<G, D, 0, stream>>>(hcur, nstart, W + (long)l * D * D,
                                      ctxT + (long)l * G * D, T);
        unsigned* hnext = bufs[l & 1];
        layer_kernel<<<layerBlocks, 128, 0, stream>>>(hcur, Wpk + (size_t)l * 2048, T,
                                                      gids, rowptr, csr,
                                                      eps + l, hnext, N);
        hcur = hnext;
    }

    // ---- readout
    readout<<<G, D, 0, stream>>>(hcur, nstart, fc1_w, fc1_b, fc2_w, fc2_b, out);
}

// Round 7
// 558.897 us; speedup vs baseline: 1.2483x; 1.2483x over previous
//
#include <hip/hip_runtime.h>

#define D 128

typedef short short8_t __attribute__((ext_vector_type(8)));
typedef float float4_t __attribute__((ext_vector_type(4)));

// CSR-build bucketing: bucket = dst >> 8 (256 nodes/bucket), NB <= 512
#define BSH 8
#define BSZ 256
#define NBLK_A 256

// ---------------------------------------------------------------- bf16 helpers
__device__ __forceinline__ float bf_lo(unsigned u) { return __uint_as_float(u << 16); }
__device__ __forceinline__ float bf_hi(unsigned u) { return __uint_as_float(u & 0xffff0000u); }
__device__ __forceinline__ unsigned to_bf1(float x) {           // RNE round to bf16
    unsigned b = __float_as_uint(x);
    return (b + 0x7fffu + ((b >> 16) & 1u)) >> 16;
}
__device__ __forceinline__ unsigned pack2(float a, float b) {
    return to_bf1(a) | (to_bf1(b) << 16);
}

// ---------------------------------------------------------------- utilities

__global__ void f32_to_bf16(const float4* __restrict__ in, uint2* __restrict__ out, long n4) {
    long i = (long)blockIdx.x * blockDim.x + threadIdx.x;
    long stride = (long)gridDim.x * blockDim.x;
    for (; i < n4; i += stride) {
        float4 v = in[i];
        out[i] = make_uint2(pack2(v.x, v.y), pack2(v.z, v.w));
    }
}

// Pack W (L x 128 x 128 fp32) into MFMA B-fragment stream.
__global__ void wpack(const float* __restrict__ W, uint4* __restrict__ Wpk, int L_) {
    int id = blockIdx.x * blockDim.x + threadIdx.x;
    if (id >= L_ * 2048) return;
    int lane = id & 63, cc = (id >> 6) & 3, t = (id >> 8) & 7, l = id >> 11;
    int n = t * 16 + (lane & 15);
    int k0 = cc * 32 + (lane >> 4) * 8;
    const float* Wb = W + (long)l * D * D;
    unsigned u0 = pack2(Wb[(long)(k0 + 0) * D + n], Wb[(long)(k0 + 1) * D + n]);
    unsigned u1 = pack2(Wb[(long)(k0 + 2) * D + n], Wb[(long)(k0 + 3) * D + n]);
    unsigned u2 = pack2(Wb[(long)(k0 + 4) * D + n], Wb[(long)(k0 + 5) * D + n]);
    unsigned u3 = pack2(Wb[(long)(k0 + 6) * D + n], Wb[(long)(k0 + 7) * D + n]);
    Wpk[id] = make_uint4(u0, u1, u2, u3);
}

// ---------------------------------------------------------------- CSR build (bucketed)

__global__ __launch_bounds__(256)
void csr_hist(const int* __restrict__ dst, int* __restrict__ Hist, int E_, int chunk) {
    __shared__ int h[512];
    int b = blockIdx.x, t = threadIdx.x;
    h[t] = 0; h[t + 256] = 0;
    __syncthreads();
    int base = b * chunk;
    int end = base + chunk; if (end > E_) end = E_;
    for (int i = base + t; i < end; i += 256)
        atomicAdd(&h[dst[i] >> BSH], 1);
    __syncthreads();
    Hist[b * 512 + t] = h[t];
    Hist[b * 512 + t + 256] = h[t + 256];
}

__global__ __launch_bounds__(256)
void csr_scan_blocks(int* __restrict__ Hist, int* __restrict__ Tot) {
    __shared__ int sc[256];
    int bkt = blockIdx.x, t = threadIdx.x;
    int v = Hist[t * 512 + bkt];
    sc[t] = v; __syncthreads();
    for (int off = 1; off < 256; off <<= 1) {
        int u = (t >= off) ? sc[t - off] : 0;
        __syncthreads();
        sc[t] += u;
        __syncthreads();
    }
    Hist[t * 512 + bkt] = sc[t] - v;          // exclusive
    if (t == 255) Tot[bkt] = sc[255];
}

__global__ __launch_bounds__(512)
void csr_scan_base(const int* __restrict__ Tot, int* __restrict__ Base, int NB) {
    __shared__ int sc[512];
    int t = threadIdx.x;
    int v = (t < NB) ? Tot[t] : 0;
    sc[t] = v; __syncthreads();
    for (int off = 1; off < 512; off <<= 1) {
        int u = (t >= off) ? sc[t - off] : 0;
        __syncthreads();
        sc[t] += u;
        __syncthreads();
    }
    Base[t] = sc[t] - v;
    if (t == NB - 1) Base[NB] = sc[t];
}

__global__ __launch_bounds__(256)
void csr_scatter(const int* __restrict__ src, const int* __restrict__ dst,
                 const int* __restrict__ Hist, const int* __restrict__ Base,
                 unsigned* __restrict__ EdgeBuf, int E_, int chunk) {
    __shared__ int cur[512];
    int b = blockIdx.x, t = threadIdx.x;
    cur[t]       = Base[t]       + Hist[b * 512 + t];
    cur[t + 256] = Base[t + 256] + Hist[b * 512 + t + 256];
    __syncthreads();
    int base = b * chunk;
    int end = base + chunk; if (end > E_) end = E_;
    for (int i = base + t; i < end; i += 256) {
        int s = src[i], dd = dst[i];
        int p = atomicAdd(&cur[dd >> BSH], 1);
        EdgeBuf[p] = (unsigned)s | ((unsigned)(dd & (BSZ - 1)) << 24);
    }
}

__global__ __launch_bounds__(256)
void csr_fill(const unsigned* __restrict__ EdgeBuf, const int* __restrict__ Base,
              int* __restrict__ rowptr, int* __restrict__ csr, int N_, int E_) {
    __shared__ int deg[256];
    __shared__ int cur[256];
    int b = blockIdx.x, t = threadIdx.x;
    int e0 = Base[b], e1 = Base[b + 1];
    deg[t] = 0;
    __syncthreads();
    for (int i = e0 + t; i < e1; i += 256)
        atomicAdd(&deg[EdgeBuf[i] >> 24], 1);
    __syncthreads();
    int v = deg[t];
    cur[t] = v; __syncthreads();
    for (int off = 1; off < 256; off <<= 1) {
        int u = (t >= off) ? cur[t - off] : 0;
        __syncthreads();
        cur[t] += u;
        __syncthreads();
    }
    int excl = cur[t] - v;
    int node = b * BSZ + t;
    if (node < N_) rowptr[node] = e0 + excl;
    cur[t] = e0 + excl;
    __syncthreads();
    for (int i = e0 + t; i < e1; i += 256) {
        unsigned ev = EdgeBuf[i];
        int p = atomicAdd(&cur[ev >> 24], 1);
        csr[p] = (int)(ev & 0x00FFFFFFu);
    }
    if (b == 0 && t == 0) rowptr[N_] = E_;
}

// ---------------------------------------------------------------- graph segment starts
__global__ void find_starts2(const int* __restrict__ g1, int n1,
                             const int* __restrict__ g2, int n2,
                             int G_, int* __restrict__ s1, int* __restrict__ s2) {
    int id = blockIdx.x * blockDim.x + threadIdx.x;
    if (id >= 2 * (G_ + 1)) return;
    const int* arr; int n; int* out; int g;
    if (id <= G_) { arr = g1; n = n1; out = s1; g = id; }
    else { arr = g2; n = n2; out = s2; g = id - (G_ + 1); }
    if (g == G_) { out[g] = n; return; }
    int lo = 0, hi = n;
    while (lo < hi) { int mid = (lo + hi) >> 1; if (arr[mid] < g) lo = mid + 1; else hi = mid; }
    out[g] = lo;
}

// ---------------------------------------------------------------- small reductions

__global__ void reduce_lead(const float* __restrict__ lead, float* __restrict__ hlead, int NL) {
    int d = threadIdx.x;
    float a0 = 0.f, a1 = 0.f, a2 = 0.f, a3 = 0.f;
    int r = 0;
    for (; r + 4 <= NL; r += 4) {
        a0 += lead[(long)r * D + d];
        a1 += lead[(long)(r + 1) * D + d];
        a2 += lead[(long)(r + 2) * D + d];
        a3 += lead[(long)(r + 3) * D + d];
    }
    for (; r < NL; ++r) a0 += lead[(long)r * D + d];
    hlead[d] = a0 + a1 + a2 + a3;
}

// fp32 per-graph segment sum: cvec[g] = segsum(init_feat)[g] + hlead
__global__ __launch_bounds__(128)
void segsum_pg(const float* __restrict__ feat, const int* __restrict__ start,
               const float* __restrict__ addv, float* __restrict__ out) {
    int g = blockIdx.x;
    int d = threadIdx.x;
    int r0 = start[g], r1 = start[g + 1];
    float a0 = 0.f, a1 = 0.f, a2 = 0.f, a3 = 0.f;
    int r = r0;
    for (; r + 4 <= r1; r += 4) {
        a0 += feat[(long)r * D + d];
        a1 += feat[(long)(r + 1) * D + d];
        a2 += feat[(long)(r + 2) * D + d];
        a3 += feat[(long)(r + 3) * D + d];
    }
    for (; r < r1; ++r) a0 += feat[(long)r * D + d];
    float s = a0 + a1 + a2 + a3;
    if (addv) s += addv[d];
    out[(long)g * D + d] = s;
}

// bf16 segsum of h -> packed hg (bf16 pairs, 64 uints/graph)
__global__ __launch_bounds__(128)
void segsum_h(const unsigned* __restrict__ hb, const int* __restrict__ start,
              unsigned* __restrict__ hgb) {
    __shared__ float part[2][64][2];
    int g = blockIdx.x, t = threadIdx.x;
    int c = t & 63, half = t >> 6;
    int r0 = start[g], r1 = start[g + 1];
    float l0=0,h0=0,l1=0,h1=0,l2=0,h2=0,l3=0,h3=0;
    int r = r0 + half;
    for (; r + 6 < r1; r += 8) {
        unsigned a = hb[(long)r * 64 + c];
        unsigned bq = hb[(long)(r + 2) * 64 + c];
        unsigned cq = hb[(long)(r + 4) * 64 + c];
        unsigned dq = hb[(long)(r + 6) * 64 + c];
        l0 += bf_lo(a);  h0 += bf_hi(a);
        l1 += bf_lo(bq); h1 += bf_hi(bq);
        l2 += bf_lo(cq); h2 += bf_hi(cq);
        l3 += bf_lo(dq); h3 += bf_hi(dq);
    }
    for (; r < r1; r += 2) { unsigned a = hb[(long)r * 64 + c]; l0 += bf_lo(a); h0 += bf_hi(a); }
    part[half][c][0] = (l0 + l1) + (l2 + l3);
    part[half][c][1] = (h0 + h1) + (h2 + h3);
    __syncthreads();
    if (t < 64) {
        float lo = part[0][t][0] + part[1][t][0];
        float hi = part[0][t][1] + part[1][t][1];
        hgb[(long)g * 64 + t] = pack2(lo, hi);
    }
}

// ---------------------------------------------------------------- graph-side GEMMs
// ctxT[l][g][c] = cvec[g] @ Wc[l][:,c] + b[l][c]
// grid = L * (G/8) blocks, 256 threads; 8 graphs/block, 4 chains/thread.
__global__ __launch_bounds__(256)
void ctx_gemm(const float* __restrict__ cvec, const float* __restrict__ Wc,
              const float* __restrict__ bb, float* __restrict__ ctxT, int Gtot) {
    __shared__ float xs[8][D];
    int bi = blockIdx.x;
    int bpl = Gtot >> 3;                 // blocks per layer
    int l = bi / bpl;
    int gb = (bi - l * bpl) * 8;
    int tid = threadIdx.x;
    for (int u = tid; u < 8 * D; u += 256)
        xs[u >> 7][u & 127] = cvec[(long)(gb + (u >> 7)) * D + (u & 127)];
    __syncthreads();
    int col = tid & 127, half = tid >> 7;
    const float* Wl = Wc + (long)l * D * D;
    const float* x0 = xs[half * 4 + 0];
    const float* x1 = xs[half * 4 + 1];
    const float* x2 = xs[half * 4 + 2];
    const float* x3 = xs[half * 4 + 3];
    float p0 = 0.f, p1 = 0.f, p2 = 0.f, p3 = 0.f;
    #pragma unroll 4
    for (int k = 0; k < D; ++k) {
        float wv = Wl[(long)k * D + col];
        p0 += x0[k] * wv; p1 += x1[k] * wv;
        p2 += x2[k] * wv; p3 += x3[k] * wv;
    }
    float bv = bb[l * D + col];
    long ob = ((long)l * Gtot + gb + half * 4) * D + col;
    ctxT[ob]         = p0 + bv;
    ctxT[ob + D]     = p1 + bv;
    ctxT[ob + 2 * D] = p2 + bv;
    ctxT[ob + 3 * D] = p3 + bv;
}

// T[g][c] = hg[g] @ Wl[:,c] + ctxT_l[g][c]
// grid = G/8 blocks, 256 threads.
__global__ __launch_bounds__(256)
void hg_gemm(const unsigned* __restrict__ hgb, const float* __restrict__ Wl,
             const float* __restrict__ ctxT_l, float* __restrict__ T) {
    __shared__ float xs[8][D];
    int gb = blockIdx.x * 8;
    int tid = threadIdx.x;
    for (int u = tid; u < 8 * 64; u += 256) {
        unsigned v = hgb[(long)gb * 64 + u];
        xs[u >> 6][(u & 63) * 2]     = bf_lo(v);
        xs[u >> 6][(u & 63) * 2 + 1] = bf_hi(v);
    }
    __syncthreads();
    int col = tid & 127, half = tid >> 7;
    const float* x0 = xs[half * 4 + 0];
    const float* x1 = xs[half * 4 + 1];
    const float* x2 = xs[half * 4 + 2];
    const float* x3 = xs[half * 4 + 3];
    float p0 = 0.f, p1 = 0.f, p2 = 0.f, p3 = 0.f;
    #pragma unroll 4
    for (int k = 0; k < D; ++k) {
        float wv = Wl[(long)k * D + col];
        p0 += x0[k] * wv; p1 += x1[k] * wv;
        p2 += x2[k] * wv; p3 += x3[k] * wv;
    }
    long ob = (long)(gb + half * 4) * D + col;
    T[ob]         = p0 + ctxT_l[ob];
    T[ob + D]     = p1 + ctxT_l[ob + D];
    T[ob + 2 * D] = p2 + ctxT_l[ob + 2 * D];
    T[ob + 3 * D] = p3 + ctxT_l[ob + 3 * D];
}

// ---------------------------------------------------------------- readout
__global__ __launch_bounds__(128)
void readout(const unsigned* __restrict__ hb, const int* __restrict__ start,
             const float* __restrict__ f1w, const float* __restrict__ f1b,
             const float* __restrict__ f2w, const float* __restrict__ f2b,
             float* __restrict__ out) {
    __shared__ float part[2][64][2];
    __shared__ float xs[D];
    __shared__ float zs[D];
    int g = blockIdx.x, t = threadIdx.x;
    int c = t & 63, half = t >> 6;
    int r0 = start[g], r1 = start[g + 1];
    float l0=0,h0=0,l1=0,h1=0;
    int r = r0 + half;
    for (; r + 2 < r1; r += 4) {
        unsigned a = hb[(long)r * 64 + c];
        unsigned bq = hb[(long)(r + 2) * 64 + c];
        l0 += bf_lo(a);  h0 += bf_hi(a);
        l1 += bf_lo(bq); h1 += bf_hi(bq);
    }
    if (r < r1) { unsigned a = hb[(long)r * 64 + c]; l0 += bf_lo(a); h0 += bf_hi(a); }
    part[half][c][0] = l0 + l1;
    part[half][c][1] = h0 + h1;
    __syncthreads();
    xs[t] = part[0][t >> 1][t & 1] + part[1][t >> 1][t & 1];
    __syncthreads();
    float p0=0,p1=0,p2=0,p3=0;
    for (int k = 0; k < D; k += 4) {
        p0 += xs[k]     * f1w[(long)k * D + t];
        p1 += xs[k + 1] * f1w[(long)(k + 1) * D + t];
        p2 += xs[k + 2] * f1w[(long)(k + 2) * D + t];
        p3 += xs[k + 3] * f1w[(long)(k + 3) * D + t];
    }
    zs[t] = fmaxf(f1b[t] + (p0 + p1) + (p2 + p3), 0.f);
    __syncthreads();
    float q0=0,q1=0,q2=0,q3=0;
    for (int k = 0; k < D; k += 4) {
        q0 += zs[k]     * f2w[(long)k * D + t];
        q1 += zs[k + 1] * f2w[(long)(k + 1) * D + t];
        q2 += zs[k + 2] * f2w[(long)(k + 2) * D + t];
        q3 += zs[k + 3] * f2w[(long)(k + 3) * D + t];
    }
    out[(long)g * D + t] = f2b[t] + (q0 + q1) + (q2 + q3);
}

// ---------------------------------------------------------------- fused GIN layer (bf16 h, MFMA)
// R5-measured version: TROWS 64, 256 threads, single-uint gather, 77.5 us.
#define TROWS 64
__global__ __launch_bounds__(256, 6)
void layer_kernel(const unsigned* __restrict__ hb, const uint4* __restrict__ Wpk_l,
                  const float* __restrict__ T, const int* __restrict__ gids,
                  const int* __restrict__ rowptr, const int* __restrict__ csr,
                  const float* __restrict__ eps_l, unsigned* __restrict__ houtb, int n) {
    __shared__ __align__(16) unsigned Minb[TROWS][68];
    int tid = threadIdx.x;
    int w = tid >> 6, lane = tid & 63;
    int w16 = w * 16;
    int rowBase = blockIdx.x * TROWS;
    int rb = rowBase + w16;
    float epsv = 1.0f + *eps_l;

    int rp = rb + lane; if (rp > n) rp = n;
    int evv = rowptr[rp];

    int e0 = __shfl(evv, 0);
    int e1 = __shfl(evv, 1);
    int idxv = (e0 + lane < e1) ? csr[e0 + lane] : 0;

    for (int i = 0; i < 16; ++i) {
        int r = rb + i;
        int deg = e1 - e0;
        int e0n = __shfl(evv, i + 1);
        int e1n = __shfl(evv, i + 2);
        int idxn = (e0n + lane < e1n) ? csr[e0n + lane] : 0;
        float sx = 0.f, sy = 0.f;
        if (r < n) {
            unsigned su = hb[(long)r * 64 + lane];
            float ax0 = epsv * bf_lo(su), ay0 = epsv * bf_hi(su);
            float ax1=0,ay1=0,ax2=0,ay2=0,ax3=0,ay3=0;
            int iv = idxv;
            int base = 0;
            while (true) {
                int m = deg - base; if (m > 64) m = 64;
                int j = 0;
                for (; j + 8 <= m; j += 8) {
                    int s0=__shfl(iv,j+0), s1=__shfl(iv,j+1), s2=__shfl(iv,j+2), s3=__shfl(iv,j+3);
                    int s4=__shfl(iv,j+4), s5=__shfl(iv,j+5), s6=__shfl(iv,j+6), s7=__shfl(iv,j+7);
                    unsigned u0=hb[(long)s0*64+lane], u1=hb[(long)s1*64+lane];
                    unsigned u2=hb[(long)s2*64+lane], u3=hb[(long)s3*64+lane];
                    unsigned u4=hb[(long)s4*64+lane], u5=hb[(long)s5*64+lane];
                    unsigned u6=hb[(long)s6*64+lane], u7=hb[(long)s7*64+lane];
                    ax0+=bf_lo(u0); ay0+=bf_hi(u0); ax1+=bf_lo(u1); ay1+=bf_hi(u1);
                    ax2+=bf_lo(u2); ay2+=bf_hi(u2); ax3+=bf_lo(u3); ay3+=bf_hi(u3);
                    ax0+=bf_lo(u4); ay0+=bf_hi(u4); ax1+=bf_lo(u5); ay1+=bf_hi(u5);
                    ax2+=bf_lo(u6); ay2+=bf_hi(u6); ax3+=bf_lo(u7); ay3+=bf_hi(u7);
                }
                for (; j < m; ++j) {
                    int s = __shfl(iv, j);
                    unsigned u = hb[(long)s * 64 + lane];
                    ax0 += bf_lo(u); ay0 += bf_hi(u);
                }
                base += 64;
                if (base >= deg) break;
                int mm = deg - base;
                iv = (lane < mm) ? csr[e0 + base + lane] : 0;
            }
            sx = (ax0 + ax1) + (ax2 + ax3);
            sy = (ay0 + ay1) + (ay2 + ay3);
        }
        Minb[w16 + i][lane] = pack2(sx, sy);
        e0 = e0n; e1 = e1n; idxv = idxn;
    }
    // No barrier: each wave's rows are private.

    int m_ = lane & 15, quad = lane >> 4;
    float4_t acc[8];
    #pragma unroll
    for (int tt = 0; tt < 8; ++tt) { acc[tt][0]=0.f; acc[tt][1]=0.f; acc[tt][2]=0.f; acc[tt][3]=0.f; }

    #pragma unroll
    for (int cc = 0; cc < 4; ++cc) {
        short8_t af = *(const short8_t*)&Minb[w16 + m_][cc * 16 + quad * 4];
        #pragma unroll
        for (int tt = 0; tt < 8; ++tt) {
            short8_t bf = *(const short8_t*)&Wpk_l[(tt * 4 + cc) * 64 + lane];
            acc[tt] = __builtin_amdgcn_mfma_f32_16x16x32_bf16(af, bf, acc[tt], 0, 0, 0);
        }
    }

    int gq[4];
    #pragma unroll
    for (int reg = 0; reg < 4; ++reg) {
        int r = rb + quad * 4 + reg;
        gq[reg] = (r < n) ? gids[r] : 0;
    }
    #pragma unroll
    for (int tt = 0; tt < 8; ++tt) {
        int col = tt * 16 + m_;
        #pragma unroll
        for (int reg = 0; reg < 4; ++reg) {
            float v = acc[tt][reg] + T[(long)gq[reg] * D + col];
            v = fmaxf(v, 0.f);
            float v2 = __shfl_xor(v, 1);
            if (!(lane & 1)) Minb[w16 + quad * 4 + reg][tt * 8 + (m_ >> 1)] = pack2(v, v2);
        }
    }
    #pragma unroll
    for (int rr = 0; rr < 4; ++rr) {
        int lrow = rr * 4 + (lane >> 4);
        int r = rowBase + w16 + lrow;
        if (r < n) {
            uint4 v = *(const uint4*)&Minb[w16 + lrow][(lane & 15) * 4];
            *(uint4*)&houtb[(long)r * 64 + (lane & 15) * 4] = v;
        }
    }
}

// ---------------------------------------------------------------- launch

static inline size_t align512(size_t x) { return (x + 511) & ~(size_t)511; }

extern "C" void kernel_launch(void* const* d_in, const int* in_sizes, int n_in,
                              void* d_out, int out_size, void* d_ws, size_t ws_size,
                              hipStream_t stream) {
    const float* x        = (const float*)d_in[0];
    const int*   src      = (const int*)d_in[1];
    const int*   dst      = (const int*)d_in[2];
    const int*   gids     = (const int*)d_in[3];
    const float* initf    = (const float*)d_in[4];
    const int*   init_gid = (const int*)d_in[5];
    const float* leadf    = (const float*)d_in[6];
    const float* W        = (const float*)d_in[7];
    const float* Wc       = (const float*)d_in[8];
    const float* b        = (const float*)d_in[9];
    const float* eps      = (const float*)d_in[10];
    const float* fc1_w    = (const float*)d_in[11];
    const float* fc1_b    = (const float*)d_in[12];
    const float* fc2_w    = (const float*)d_in[13];
    const float* fc2_b    = (const float*)d_in[14];
    float* out = (float*)d_out;

    const int N  = in_sizes[0] / D;
    const int E  = in_sizes[1];
    const int NI = in_sizes[4] / D;
    const int NL = in_sizes[6] / D;
    const int L  = in_sizes[10];

    // workspace carve-up
    char* p = (char*)d_ws;
    unsigned* xb  = (unsigned*)p; p += align512((size_t)N * 64 * 4);
    unsigned* hAb = (unsigned*)p; p += align512((size_t)N * 64 * 4);
    unsigned* hBb = (unsigned*)p; p += align512((size_t)N * 64 * 4);
    const int G = 1024;
    float* T     = (float*)p; p += align512((size_t)G * D * 4);
    float* ctxT  = (float*)p; p += align512((size_t)L * G * D * 4);
    float* cvec  = (float*)p; p += align512((size_t)G * D * 4);
    float* hlead = (float*)p; p += align512((size_t)D * 4);
    unsigned* hgb = (unsigned*)p; p += align512((size_t)G * 64 * 4);
    int* rowptr  = (int*)p;   p += align512((size_t)(N + 1) * 4);
    int* csr     = (int*)p;   p += align512((size_t)E * 4);
    unsigned* EdgeBuf = (unsigned*)p; p += align512((size_t)E * 4);
    int* Hist    = (int*)p;   p += align512((size_t)NBLK_A * 512 * 4);
    int* Tot     = (int*)p;   p += align512((size_t)520 * 4);
    int* Base    = (int*)p;   p += align512((size_t)520 * 4);
    int* nstart  = (int*)p;   p += align512((size_t)(G + 1) * 4);
    int* istart  = (int*)p;   p += align512((size_t)(G + 1) * 4);
    uint4* Wpk   = (uint4*)p; p += align512((size_t)L * 2048 * 16);
    (void)ws_size; (void)n_in;

    const int NB = (N + BSZ - 1) / BSZ;
    const int chunk = (E + NBLK_A - 1) / NBLK_A;

    // ---- CSR build (bucketed)
    csr_hist<<<NBLK_A, 256, 0, stream>>>(dst, Hist, E, chunk);
    csr_scan_blocks<<<NB, 256, 0, stream>>>(Hist, Tot);
    csr_scan_base<<<1, 512, 0, stream>>>(Tot, Base, NB);
    csr_scatter<<<NBLK_A, 256, 0, stream>>>(src, dst, Hist, Base, EdgeBuf, E, chunk);
    csr_fill<<<NB, 256, 0, stream>>>(EdgeBuf, Base, rowptr, csr, N, E);

    // ---- bf16 copy of x; packed W fragments; segment starts
    f32_to_bf16<<<2048, 256, 0, stream>>>((const float4*)x, (uint2*)xb, (long)N * D / 4);
    wpack<<<(L * 2048 + 255) / 256, 256, 0, stream>>>(W, Wpk, L);
    find_starts2<<<(2 * (G + 1) + 255) / 256, 256, 0, stream>>>(gids, N, init_gid, NI,
                                                                G, nstart, istart);

    // ---- layer-invariant context: cvec then ctxT for all layers
    reduce_lead<<<1, D, 0, stream>>>(leadf, hlead, NL);
    segsum_pg<<<G, D, 0, stream>>>(initf, istart, hlead, cvec);
    ctx_gemm<<<L * (G / 8), 256, 0, stream>>>(cvec, Wc, b, ctxT, G);

    const unsigned* hcur = xb;
    unsigned* bufs[2] = { hAb, hBb };
    int layerBlocks = (N + TROWS - 1) / TROWS;
    for (int l = 0; l < L; ++l) {
        segsum_h<<<G, 128, 0, stream>>>(hcur, nstart, hgb);
        hg_gemm<<<G / 8, 256, 0, stream>>>(hgb, W + (long)l * D * D,
                                           ctxT + (long)l * G * D, T);
        unsigned* hnext = bufs[l & 1];
        layer_kernel<<<layerBlocks, 256, 0, stream>>>(hcur, Wpk + (size_t)l * 2048, T,
                                                      gids, rowptr, csr,
                                                      eps + l, hnext, N);
        hcur = hnext;
    }

    // ---- readout
    readout<<<G, 128, 0, stream>>>(hcur, nstart, fc1_w, fc1_b, fc2_w, fc2_b, out);
}